// Round 11
// baseline (255.101 us; speedup 1.0000x reference)
//
#include <hip/hip_runtime.h>
#include <hip/hip_bf16.h>
#include <math.h>

typedef __attribute__((ext_vector_type(8))) short short8;   // 8 bf16 (4 VGPRs)
typedef __attribute__((ext_vector_type(4))) float f32x4;
typedef __attribute__((ext_vector_type(8))) unsigned short us8;

__device__ __forceinline__ float us2f(unsigned short u) {
    return __uint_as_float(((unsigned)u) << 16);
}
__device__ __forceinline__ unsigned short f2us_rtn(float f) {
    return (unsigned short)__bfloat16_as_ushort(__float2bfloat16(f));  // RTN
}

// ---- k1: zero deg[Npad] + as/ad x4 (must precede count/gemm1) ---------------
__global__ void zero_kernel(float* __restrict__ as1, float* __restrict__ ad1,
                            float* __restrict__ as2, float* __restrict__ ad2,
                            int* __restrict__ deg, int N, int Npad) {
    int idx = blockIdx.x * blockDim.x + threadIdx.x;
    if (idx < 4 * N) {
        if (idx < N) as1[idx] = 0.f;
        else if (idx < 2 * N) ad1[idx - N] = 0.f;
        else if (idx < 3 * N) as2[idx - 2 * N] = 0.f;
        else ad2[idx - 3 * N] = 0.f;
        return;
    }
    idx -= 4 * N;
    if (idx < Npad) deg[idx] = 0;
}

// ---- k2: prep-convert blocks (W^T bf16 x3 + obs->bf16)  ||  count blocks ----
__global__ __launch_bounds__(256, 1) void prep_count(const float* __restrict__ Wa,
                                                     const float* __restrict__ Wb,
                                                     const float* __restrict__ Wc,
                                                     const float* __restrict__ obs,
                                                     unsigned short* __restrict__ TA,
                                                     unsigned short* __restrict__ TB,
                                                     unsigned short* __restrict__ TC,
                                                     unsigned short* __restrict__ obsb,
                                                     int K, int Nn, int nObs8, int wblocks,
                                                     const int* __restrict__ dstA,
                                                     int* __restrict__ deg, int E, int Etot) {
    const int bid = blockIdx.x;
    if (bid < wblocks) {
        const int tot = K * Nn;
        int idx = bid * 256 + threadIdx.x;
        if (idx < 3 * tot) {
            const float* W;
            unsigned short* T;
            if (idx < tot) { W = Wa; T = TA; }
            else if (idx < 2 * tot) { W = Wb; T = TB; idx -= tot; }
            else { W = Wc; T = TC; idx -= 2 * tot; }
            const int n = idx / K, k = idx - n * K;
            T[idx] = f2us_rtn(W[(size_t)k * Nn + n]);
            return;
        }
        idx -= 3 * tot;
        if (idx < nObs8) {
            const float4 a = *(const float4*)(obs + (size_t)idx * 8);
            const float4 b = *(const float4*)(obs + (size_t)idx * 8 + 4);
            const float f[8] = {a.x, a.y, a.z, a.w, b.x, b.y, b.z, b.w};
            short8 o;
#pragma unroll
            for (int e = 0; e < 8; e++) o[e] = (short)f2us_rtn(f[e]);
            *(short8*)(obsb + (size_t)idx * 8) = o;
        }
    } else {
        const int e = (bid - wblocks) * 256 + threadIdx.x;
        if (e < Etot) {
            const int d = (e < E) ? dstA[e] : (e - E);
            atomicAdd(&deg[d], 1);
        }
    }
}

#define LP 72
// ---- R1-proven 64x128 GEMM tile + fused as/ad dots (2-barrier K-loop) -------
__device__ __forceinline__ void gemm_tile(const unsigned short* __restrict__ A,
                                          const unsigned short* __restrict__ Bt,
                                          const float* __restrict__ avs,
                                          const float* __restrict__ avd,
                                          float* __restrict__ as_,
                                          float* __restrict__ ad_,
                                          unsigned short* __restrict__ C,
                                          int M, int Nn, int K, int row0, int col0,
                                          unsigned short* sA, unsigned short* sB) {
    const int tid = threadIdx.x;
    const int wave = tid >> 6, lane = tid & 63;
    const int m16 = lane & 15, quad = lane >> 4;
    const int wr = (wave >> 1) * 32, wc = (wave & 1) * 64;
    const int ar = tid >> 2, akc = (tid & 3) * 8;
    const int bkc = (tid & 7) * 8, bcb = tid >> 3;
    const int gr = (row0 + ar) < M ? (row0 + ar) : (M - 1);
    const unsigned short* Arow = A + (size_t)gr * K + akc;
    const unsigned short* Bcol = Bt + (size_t)(col0 + bcb) * K + bkc;

    short8 rA0, rA1, rb0, rb1, rb2, rb3;
    auto LOADT = [&](int k0) {
        rA0 = *(const short8*)(Arow + k0);
        rA1 = *(const short8*)(Arow + k0 + 32);
        rb0 = *(const short8*)(Bcol + k0);
        rb1 = *(const short8*)(Bcol + (size_t)32 * K + k0);
        rb2 = *(const short8*)(Bcol + (size_t)64 * K + k0);
        rb3 = *(const short8*)(Bcol + (size_t)96 * K + k0);
    };
    auto STORET = [&]() {
        *(short8*)&sA[ar * LP + akc]      = rA0;
        *(short8*)&sA[ar * LP + akc + 32] = rA1;
        *(short8*)&sB[bcb * LP + bkc]        = rb0;
        *(short8*)&sB[(bcb + 32) * LP + bkc] = rb1;
        *(short8*)&sB[(bcb + 64) * LP + bkc] = rb2;
        *(short8*)&sB[(bcb + 96) * LP + bkc] = rb3;
    };

    f32x4 acc[2][4] = {};
    LOADT(0);
    STORET();
    __syncthreads();
    for (int k0 = 0; k0 < K; k0 += 64) {
        const bool more = (k0 + 64) < K;
        if (more) LOADT(k0 + 64);           // in flight under MFMA phase
#pragma unroll
        for (int ks = 0; ks < 2; ks++) {
            short8 ah[2];
#pragma unroll
            for (int mi = 0; mi < 2; mi++)
                ah[mi] = *(const short8*)&sA[(wr + mi * 16 + m16) * LP + ks * 32 + quad * 8];
#pragma unroll
            for (int ni = 0; ni < 4; ni++) {
                const short8 bv = *(const short8*)&sB[(wc + ni * 16 + m16) * LP + ks * 32 + quad * 8];
#pragma unroll
                for (int mi = 0; mi < 2; mi++)
                    acc[mi][ni] = __builtin_amdgcn_mfma_f32_16x16x32_bf16(ah[mi], bv, acc[mi][ni], 0, 0, 0);
            }
        }
        __syncthreads();
        if (more) { STORET(); __syncthreads(); }
    }
    // epilogue: C/D layout col=lane&15, row=quad*4+r [m89-verified]
    float ps[2][4] = {}, pd[2][4] = {};
#pragma unroll
    for (int mi = 0; mi < 2; mi++) {
        const int orow_base = row0 + wr + mi * 16 + quad * 4;
#pragma unroll
        for (int ni = 0; ni < 4; ni++) {
            const int ocol = col0 + wc + ni * 16 + m16;
            const float asv = avs[ocol], adv = avd[ocol];
#pragma unroll
            for (int r = 0; r < 4; r++) {
                const int orow = orow_base + r;
                if (orow < M) {
                    const float v = acc[mi][ni][r];
                    C[(size_t)orow * Nn + ocol] = f2us_rtn(v);
                    ps[mi][r] = fmaf(v, asv, ps[mi][r]);
                    pd[mi][r] = fmaf(v, adv, pd[mi][r]);
                }
            }
        }
    }
#pragma unroll
    for (int mi = 0; mi < 2; mi++)
#pragma unroll
        for (int r = 0; r < 4; r++)
#pragma unroll
            for (int off = 1; off < 16; off <<= 1) {
                ps[mi][r] += __shfl_xor(ps[mi][r], off);
                pd[mi][r] += __shfl_xor(pd[mi][r], off);
            }
    if (m16 == 0) {
#pragma unroll
        for (int mi = 0; mi < 2; mi++) {
            const int orow_base = row0 + wr + mi * 16 + quad * 4;
#pragma unroll
            for (int r = 0; r < 4; r++) {
                const int orow = orow_base + r;
                if (orow < M) {
                    atomicAdd(&as_[orow], ps[mi][r]);
                    atomicAdd(&ad_[orow], pd[mi][r]);
                }
            }
        }
    }
}

// ---- 256-thread int4 scan over padded deg (R9-proven body) ------------------
__device__ __forceinline__ void scan_body(const int* __restrict__ deg,
                                          int* __restrict__ offs,
                                          int* __restrict__ cursor,
                                          int N, int per, int* sums) {
    const int t = threadIdx.x;
    const int base = t * per;
    int s = 0;
    for (int i = 0; i < per; i += 4) {
        const int4 v = *(const int4*)(deg + base + i);
        s += v.x + v.y + v.z + v.w;
    }
    sums[t] = s;
    __syncthreads();
    for (int off = 1; off < 256; off <<= 1) {
        const int add = (t >= off) ? sums[t - off] : 0;
        __syncthreads();
        sums[t] += add;
        __syncthreads();
    }
    int run = (t > 0) ? sums[t - 1] : 0;
    for (int i = 0; i < per; i += 4) {
        const int4 v = *(const int4*)(deg + base + i);
        const int p = base + i;
        const int vv[4] = {v.x, v.y, v.z, v.w};
#pragma unroll
        for (int j = 0; j < 4; j++) {
            if (p + j < N) { offs[p + j] = run; cursor[p + j] = run; }
            run += vv[j];
        }
    }
    if (t == 255) offs[N] = run;   // pads are zero -> run == total
}

// ---- k3: scan (block 0)  ||  gemm1 col-half 0 (blocks 1..nrow) --------------
__global__ __launch_bounds__(256, 1) void gemm_scan(const unsigned short* __restrict__ A,
                                                    const unsigned short* __restrict__ Bt,
                                                    const float* __restrict__ avs,
                                                    const float* __restrict__ avd,
                                                    float* __restrict__ as_,
                                                    float* __restrict__ ad_,
                                                    unsigned short* __restrict__ C,
                                                    int M, int Nn, int K,
                                                    const int* __restrict__ deg,
                                                    int* __restrict__ offs,
                                                    int* __restrict__ cursor, int N, int per) {
    __shared__ unsigned short sA[64 * LP];
    __shared__ unsigned short sB[128 * LP];
    __shared__ int sums[256];
    const int bid = blockIdx.x;
    if (bid == 0) {
        scan_body(deg, offs, cursor, N, per, sums);
    } else {
        gemm_tile(A, Bt, avs, avd, as_, ad_, C, M, Nn, K, (bid - 1) * 64, 0, sA, sB);
    }
}

// ---- k4: gemm1 col-half 1 (blocks 0..nrow-1)  ||  scatter blocks ------------
__global__ __launch_bounds__(256, 1) void gemm_scatter(const unsigned short* __restrict__ A,
                                                       const unsigned short* __restrict__ Bt,
                                                       const float* __restrict__ avs,
                                                       const float* __restrict__ avd,
                                                       float* __restrict__ as_,
                                                       float* __restrict__ ad_,
                                                       unsigned short* __restrict__ C,
                                                       int M, int Nn, int K, int nrow,
                                                       const int* __restrict__ srcA,
                                                       const int* __restrict__ dstA,
                                                       int* __restrict__ cursor,
                                                       int* __restrict__ esrc, int E, int Etot) {
    __shared__ unsigned short sA[64 * LP];
    __shared__ unsigned short sB[128 * LP];
    const int bid = blockIdx.x;
    if (bid < nrow) {
        gemm_tile(A, Bt, avs, avd, as_, ad_, C, M, Nn, K, bid * 64, 128, sA, sB);
    } else {
        const int e = (bid - nrow) * 256 + threadIdx.x;
        if (e < Etot) {
            int s, d;
            if (e < E) { s = srcA[e]; d = dstA[e]; } else { s = d = e - E; }
            const int slot = atomicAdd(&cursor[d], 1);
            esrc[slot] = s;
        }
    }
}

// ---- standalone GAT gemm (layer 2, R1-proven) -------------------------------
__global__ __launch_bounds__(256) void gemm_mfma(const unsigned short* __restrict__ A,
                                                 const unsigned short* __restrict__ Bt,
                                                 const float* __restrict__ avs,
                                                 const float* __restrict__ avd,
                                                 float* __restrict__ as_,
                                                 float* __restrict__ ad_,
                                                 unsigned short* __restrict__ C,
                                                 int M, int Nn, int K) {
    __shared__ unsigned short sA[64 * LP];
    __shared__ unsigned short sB[128 * LP];
    gemm_tile(A, Bt, avs, avd, as_, ad_, C, M, Nn, K,
              blockIdx.x * 64, blockIdx.y * 128, sA, sB);
}

// ---------------- MLP gemm + fused head (proven R1 body) ---------------------
__global__ __launch_bounds__(256) void gemm_head(const unsigned short* __restrict__ A,
                                                 const unsigned short* __restrict__ Bt,
                                                 const float* __restrict__ bias1,
                                                 const float* __restrict__ W2,
                                                 const float* __restrict__ bias2,
                                                 float* __restrict__ out,
                                                 int M, int K, int Aout) {
    __shared__ unsigned short sA[64 * LP];
    __shared__ unsigned short sB[256 * LP];
    __shared__ float pLDS[2][64][8];
    const int tid = threadIdx.x;
    const int wave = tid >> 6, lane = tid & 63;
    const int m16 = lane & 15, quad = lane >> 4;
    const int row0 = blockIdx.x * 64;
    const int wr = (wave >> 1) * 32, wc = (wave & 1) * 128;
    const int ar = tid >> 2, akc = (tid & 3) * 8;
    const int bkc = (tid & 7) * 8, bcb = tid >> 3;
    const int gr = (row0 + ar) < M ? (row0 + ar) : (M - 1);
    const unsigned short* Arow = A + (size_t)gr * K + akc;
    const unsigned short* Bcol = Bt + (size_t)bcb * K + bkc;

    short8 rA0, rA1, rb[8];
    auto LOADT = [&](int k0) {
        rA0 = *(const short8*)(Arow + k0);
        rA1 = *(const short8*)(Arow + k0 + 32);
#pragma unroll
        for (int q = 0; q < 8; q++)
            rb[q] = *(const short8*)(Bcol + (size_t)(32 * q) * K + k0);
    };
    auto STORET = [&]() {
        *(short8*)&sA[ar * LP + akc]      = rA0;
        *(short8*)&sA[ar * LP + akc + 32] = rA1;
#pragma unroll
        for (int q = 0; q < 8; q++)
            *(short8*)&sB[(bcb + 32 * q) * LP + bkc] = rb[q];
    };

    f32x4 acc[2][8] = {};
    LOADT(0);
    STORET();
    __syncthreads();
    for (int k0 = 0; k0 < K; k0 += 64) {
        const bool more = (k0 + 64) < K;
        if (more) LOADT(k0 + 64);
#pragma unroll
        for (int ks = 0; ks < 2; ks++) {
            short8 ah[2];
#pragma unroll
            for (int mi = 0; mi < 2; mi++)
                ah[mi] = *(const short8*)&sA[(wr + mi * 16 + m16) * LP + ks * 32 + quad * 8];
#pragma unroll
            for (int ni = 0; ni < 8; ni++) {
                const short8 bv = *(const short8*)&sB[(wc + ni * 16 + m16) * LP + ks * 32 + quad * 8];
#pragma unroll
                for (int mi = 0; mi < 2; mi++)
                    acc[mi][ni] = __builtin_amdgcn_mfma_f32_16x16x32_bf16(ah[mi], bv, acc[mi][ni], 0, 0, 0);
            }
        }
        __syncthreads();
        if (more) { STORET(); __syncthreads(); }
    }
    float p[2][4][8] = {};
#pragma unroll
    for (int ni = 0; ni < 8; ni++) {
        const int ocol = wc + ni * 16 + m16;
        const float b1v = bias1[ocol];
        float w2[8];
#pragma unroll
        for (int a = 0; a < 8; a++) w2[a] = W2[ocol * 8 + a];
#pragma unroll
        for (int mi = 0; mi < 2; mi++)
#pragma unroll
            for (int r = 0; r < 4; r++) {
                const float v = fmaxf(acc[mi][ni][r] + b1v, 0.f);
#pragma unroll
                for (int a = 0; a < 8; a++) p[mi][r][a] = fmaf(v, w2[a], p[mi][r][a]);
            }
    }
#pragma unroll
    for (int off = 1; off < 16; off <<= 1)
#pragma unroll
        for (int mi = 0; mi < 2; mi++)
#pragma unroll
            for (int r = 0; r < 4; r++)
#pragma unroll
                for (int a = 0; a < 8; a++) p[mi][r][a] += __shfl_xor(p[mi][r][a], off);
    if (m16 == 0) {
        const int half = wc >> 7;
#pragma unroll
        for (int mi = 0; mi < 2; mi++) {
            const int lrow = wr + mi * 16 + quad * 4;
#pragma unroll
            for (int r = 0; r < 4; r++)
#pragma unroll
                for (int a = 0; a < 8; a++) pLDS[half][lrow + r][a] = p[mi][r][a];
        }
    }
    __syncthreads();
#pragma unroll
    for (int u = 0; u < 2; u++) {
        const int idx = tid * 2 + u;
        const int lrow = idx >> 3, a = idx & 7;
        const int orow = row0 + lrow;
        if (orow < M && a < Aout)
            out[(size_t)orow * Aout + a] =
                tanhf(pLDS[0][lrow][a] + pLDS[1][lrow][a] + bias2[a]);
    }
}
#undef LP

// ---- fused softmax+aggregation (R10-proven: tail-guarded gathers) -----------
__global__ __launch_bounds__(256) void agg_kernel(const unsigned short* __restrict__ hb,
                                                  const int* __restrict__ offs,
                                                  const int* __restrict__ esrc,
                                                  const float* __restrict__ as_,
                                                  const float* __restrict__ ad_,
                                                  const float* __restrict__ bias,
                                                  unsigned short* __restrict__ xout, int N) {
    const int n = __builtin_amdgcn_readfirstlane(blockIdx.x * 4 + (threadIdx.x >> 6));
    if (n >= N) return;
    const int lane = threadIdx.x & 63;
    const int half = lane >> 5;
    const int f0 = (lane & 31) * 8;
    const int b = offs[n], e2 = offs[n + 1];
    const float adn = ad_[n];
    float a[8] = {};
    float wsum = 0.f;
    for (int c0 = b; c0 < e2; c0 += 16) {
        const int rem = e2 - c0;
        const int lim = rem < 16 ? rem : 16;
        int s = 0;
        float w = 0.f;
        if (lane < 16) {
            const int j = c0 + lane;
            const int jj = j < e2 ? j : e2 - 1;     // self-loop guarantees >= 1 edge
            s = esrc[jj];
            if (j < e2) {
                float v = as_[s] + adn;
                v = v > 0.f ? v : 0.2f * v;
                w = __expf(v);
                wsum += w;
            }
        }
        us8 pv[8];
        float wb[8];
#pragma unroll
        for (int u = 0; u < 8; u++) {
            const int el = 2 * u + half;
            const int su = __shfl(s, el);
            wb[u] = __shfl(w, el);
            if (el < lim)
                pv[u] = *(const us8*)(hb + (unsigned)((su << 8) + f0));
        }
#pragma unroll
        for (int u = 0; u < 8; u++) {
            if (2 * u + half < lim) {
#pragma unroll
                for (int j2 = 0; j2 < 8; j2++)
                    a[j2] = fmaf(wb[u], us2f(pv[u][j2]), a[j2]);
            }
        }
    }
#pragma unroll
    for (int j2 = 0; j2 < 8; j2++) a[j2] += __shfl_xor(a[j2], 32);
#pragma unroll
    for (int off = 32; off; off >>= 1) wsum += __shfl_xor(wsum, off);
    const float inv = 1.0f / (wsum + 1e-16f);
    if (half == 0) {
        const float4 b0 = *(const float4*)(bias + f0);
        const float4 b1 = *(const float4*)(bias + f0 + 4);
        const float bb[8] = {b0.x, b0.y, b0.z, b0.w, b1.x, b1.y, b1.z, b1.w};
        us8 o;
#pragma unroll
        for (int j2 = 0; j2 < 8; j2++)
            o[j2] = f2us_rtn(fmaxf(a[j2] * inv + bb[j2], 0.f));
        *(us8*)(xout + (unsigned)((n << 8) + f0)) = o;
    }
}

extern "C" void kernel_launch(void* const* d_in, const int* in_sizes, int n_in,
                              void* d_out, int out_size, void* d_ws, size_t ws_size,
                              hipStream_t stream) {
    const float* obs = (const float*)d_in[0];
    const int* eidx  = (const int*)d_in[1];
    const float* W1  = (const float*)d_in[2];
    const float* a1s = (const float*)d_in[3];
    const float* a1d = (const float*)d_in[4];
    const float* b1  = (const float*)d_in[5];
    const float* W2  = (const float*)d_in[6];
    const float* a2s = (const float*)d_in[7];
    const float* a2d = (const float*)d_in[8];
    const float* b2v = (const float*)d_in[9];
    const float* Wm1 = (const float*)d_in[10];
    const float* bm1 = (const float*)d_in[11];
    const float* Wm2 = (const float*)d_in[12];
    const float* bm2 = (const float*)d_in[13];
    float* out = (float*)d_out;

    const int Hh = in_sizes[3];            // 256
    const int Dd = in_sizes[2] / Hh;       // 256
    const int N  = in_sizes[0] / Dd;       // 20000
    const int E  = in_sizes[1] / 2;        // 320000
    const int Etot = E + N;                // 340000 (with self-loops)
    const int Aout = in_sizes[12] / Hh;    // 8

    const int* srcA = eidx;
    const int* dstA = eidx + E;

    // 256-thread scan geometry
    int per = (N + 255) / 256;
    per = (per + 3) & ~3;                  // multiple of 4 (int4 loads)
    const int Npad = 256 * per;            // 20480 at N=20000

    size_t off = 0;
    char* ws = (char*)d_ws;
    auto alloc = [&](size_t bytes) -> char* {
        char* p = ws + off;
        off = (off + bytes + 15) & ~(size_t)15;
        return p;
    };
    unsigned short* h    = (unsigned short*)alloc((size_t)N * Hh * 2);
    unsigned short* xb   = (unsigned short*)alloc((size_t)N * Hh * 2);
    unsigned short* obsb = (unsigned short*)alloc((size_t)N * Dd * 2);
    float* as1   = (float*)alloc((size_t)N * 4);
    float* ad1   = (float*)alloc((size_t)N * 4);
    float* as2   = (float*)alloc((size_t)N * 4);
    float* ad2   = (float*)alloc((size_t)N * 4);
    int* deg     = (int*)alloc((size_t)Npad * 4);
    int* offs    = (int*)alloc((size_t)(N + 1) * 4);
    int* cursor  = (int*)alloc((size_t)N * 4);
    int* esrc    = (int*)alloc((size_t)Etot * 4);
    const size_t wsz = (size_t)Dd * Hh;    // 65536
    unsigned short* W1t = (unsigned short*)alloc(wsz * 2);
    unsigned short* W2t = (unsigned short*)alloc(wsz * 2);
    unsigned short* Wmt = (unsigned short*)alloc(wsz * 2);

    const int eg = (Etot + 255) / 256;           // 1329
    const int nrow = (N + 63) / 64;              // 313
    const int nb4 = (N + 3) / 4;
    const int nObs8 = N * Dd / 8;                // 640000
    const int nWork = 3 * (int)wsz + nObs8;      // 836608 convert items
    const int wblocks = (nWork + 255) / 256;     // 3268

    // ---- k1: zero (deg, as/ad) ----
    zero_kernel<<<(4 * N + Npad + 255) / 256, 256, 0, stream>>>(
        as1, ad1, as2, ad2, deg, N, Npad);

    // ---- k2: prep-convert || count ----
    prep_count<<<wblocks + eg, 256, 0, stream>>>(
        W1, W2, Wm1, obs, W1t, W2t, Wmt, obsb, Dd, Hh, nObs8, wblocks,
        dstA, deg, E, Etot);

    // ---- k3: scan || gemm1 col-half 0 ----
    gemm_scan<<<1 + nrow, 256, 0, stream>>>(
        obsb, W1t, a1s, a1d, as1, ad1, h, N, Hh, Dd,
        deg, offs, cursor, N, per);

    // ---- k4: gemm1 col-half 1 || scatter ----
    gemm_scatter<<<nrow + eg, 256, 0, stream>>>(
        obsb, W1t, a1s, a1d, as1, ad1, h, N, Hh, Dd, nrow,
        srcA, dstA, cursor, esrc, E, Etot);

    // ---- k5: agg1 ----
    agg_kernel<<<nb4, 256, 0, stream>>>(h, offs, esrc, as1, ad1, b1, xb, N);

    // ---- k6: GAT layer 2 gemm ----
    gemm_mfma<<<dim3(nrow, Hh / 128), 256, 0, stream>>>(xb, W2t, a2s, a2d, as2, ad2, h, N, Hh, Hh);

    // ---- k7: agg2 ----
    agg_kernel<<<nb4, 256, 0, stream>>>(h, offs, esrc, as2, ad2, b2v, xb, N);

    // ---- k8: MLP + head (fused) ----
    gemm_head<<<nrow, 256, 0, stream>>>(xb, Wmt, bm1, Wm2, bm2, out, N, Hh, Aout);
}

// Round 12
// 251.499 us; speedup vs baseline: 1.0143x; 1.0143x over previous
//
#include <hip/hip_runtime.h>
#include <hip/hip_bf16.h>
#include <math.h>

typedef __attribute__((ext_vector_type(8))) short short8;   // 8 bf16 (4 VGPRs)
typedef __attribute__((ext_vector_type(4))) float f32x4;
typedef __attribute__((ext_vector_type(8))) unsigned short us8;

__device__ __forceinline__ float us2f(unsigned short u) {
    return __uint_as_float(((unsigned)u) << 16);
}
__device__ __forceinline__ unsigned short f2us_rtn(float f) {
    return (unsigned short)__bfloat16_as_ushort(__float2bfloat16(f));  // RTN
}

// ---- prep: W^T bf16 x3 + obs fp32->bf16 + zero (as/ad x4, deg[Npad]) --------
__global__ void prep_zero(const float* __restrict__ Wa, const float* __restrict__ Wb,
                          const float* __restrict__ Wc, const float* __restrict__ obs,
                          unsigned short* __restrict__ TA, unsigned short* __restrict__ TB,
                          unsigned short* __restrict__ TC, unsigned short* __restrict__ obsb,
                          float* __restrict__ as1, float* __restrict__ ad1,
                          float* __restrict__ as2, float* __restrict__ ad2,
                          int* __restrict__ deg,
                          int K, int Nn, int N, int Npad, int nObs8) {
    const int tot = K * Nn;
    int idx = blockIdx.x * blockDim.x + threadIdx.x;
    if (idx < 3 * tot) {
        const float* W;
        unsigned short* T;
        if (idx < tot) { W = Wa; T = TA; }
        else if (idx < 2 * tot) { W = Wb; T = TB; idx -= tot; }
        else { W = Wc; T = TC; idx -= 2 * tot; }
        const int n = idx / K, k = idx - n * K;
        T[idx] = f2us_rtn(W[(size_t)k * Nn + n]);
        return;
    }
    idx -= 3 * tot;
    if (idx < 4 * N) {
        if (idx < N) as1[idx] = 0.f;
        else if (idx < 2 * N) ad1[idx - N] = 0.f;
        else if (idx < 3 * N) as2[idx - 2 * N] = 0.f;
        else ad2[idx - 3 * N] = 0.f;
        return;
    }
    idx -= 4 * N;
    if (idx < Npad) { deg[idx] = 0; return; }
    idx -= Npad;
    if (idx < nObs8) {
        const float4 a = *(const float4*)(obs + (size_t)idx * 8);
        const float4 b = *(const float4*)(obs + (size_t)idx * 8 + 4);
        const float f[8] = {a.x, a.y, a.z, a.w, b.x, b.y, b.z, b.w};
        short8 o;
#pragma unroll
        for (int e = 0; e < 8; e++) o[e] = (short)f2us_rtn(f[e]);
        *(short8*)(obsb + (size_t)idx * 8) = o;
    }
}

#define LP 72
// ---- R1-proven 64x128 GEMM tile + fused as/ad dots (2-barrier K-loop) -------
__device__ __forceinline__ void gemm_tile(const unsigned short* __restrict__ A,
                                          const unsigned short* __restrict__ Bt,
                                          const float* __restrict__ avs,
                                          const float* __restrict__ avd,
                                          float* __restrict__ as_,
                                          float* __restrict__ ad_,
                                          unsigned short* __restrict__ C,
                                          int M, int Nn, int K, int row0, int col0,
                                          unsigned short* sA, unsigned short* sB) {
    const int tid = threadIdx.x;
    const int wave = tid >> 6, lane = tid & 63;
    const int m16 = lane & 15, quad = lane >> 4;
    const int wr = (wave >> 1) * 32, wc = (wave & 1) * 64;
    const int ar = tid >> 2, akc = (tid & 3) * 8;
    const int bkc = (tid & 7) * 8, bcb = tid >> 3;
    const int gr = (row0 + ar) < M ? (row0 + ar) : (M - 1);
    const unsigned short* Arow = A + (size_t)gr * K + akc;
    const unsigned short* Bcol = Bt + (size_t)(col0 + bcb) * K + bkc;

    short8 rA0, rA1, rb0, rb1, rb2, rb3;
    auto LOADT = [&](int k0) {
        rA0 = *(const short8*)(Arow + k0);
        rA1 = *(const short8*)(Arow + k0 + 32);
        rb0 = *(const short8*)(Bcol + k0);
        rb1 = *(const short8*)(Bcol + (size_t)32 * K + k0);
        rb2 = *(const short8*)(Bcol + (size_t)64 * K + k0);
        rb3 = *(const short8*)(Bcol + (size_t)96 * K + k0);
    };
    auto STORET = [&]() {
        *(short8*)&sA[ar * LP + akc]      = rA0;
        *(short8*)&sA[ar * LP + akc + 32] = rA1;
        *(short8*)&sB[bcb * LP + bkc]        = rb0;
        *(short8*)&sB[(bcb + 32) * LP + bkc] = rb1;
        *(short8*)&sB[(bcb + 64) * LP + bkc] = rb2;
        *(short8*)&sB[(bcb + 96) * LP + bkc] = rb3;
    };

    f32x4 acc[2][4] = {};
    LOADT(0);
    STORET();
    __syncthreads();
    for (int k0 = 0; k0 < K; k0 += 64) {
        const bool more = (k0 + 64) < K;
        if (more) LOADT(k0 + 64);           // in flight under MFMA phase
#pragma unroll
        for (int ks = 0; ks < 2; ks++) {
            short8 ah[2];
#pragma unroll
            for (int mi = 0; mi < 2; mi++)
                ah[mi] = *(const short8*)&sA[(wr + mi * 16 + m16) * LP + ks * 32 + quad * 8];
#pragma unroll
            for (int ni = 0; ni < 4; ni++) {
                const short8 bv = *(const short8*)&sB[(wc + ni * 16 + m16) * LP + ks * 32 + quad * 8];
#pragma unroll
                for (int mi = 0; mi < 2; mi++)
                    acc[mi][ni] = __builtin_amdgcn_mfma_f32_16x16x32_bf16(ah[mi], bv, acc[mi][ni], 0, 0, 0);
            }
        }
        __syncthreads();
        if (more) { STORET(); __syncthreads(); }
    }
    // epilogue: C/D layout col=lane&15, row=quad*4+r [m89-verified]
    float ps[2][4] = {}, pd[2][4] = {};
#pragma unroll
    for (int mi = 0; mi < 2; mi++) {
        const int orow_base = row0 + wr + mi * 16 + quad * 4;
#pragma unroll
        for (int ni = 0; ni < 4; ni++) {
            const int ocol = col0 + wc + ni * 16 + m16;
            const float asv = avs[ocol], adv = avd[ocol];
#pragma unroll
            for (int r = 0; r < 4; r++) {
                const int orow = orow_base + r;
                if (orow < M) {
                    const float v = acc[mi][ni][r];
                    C[(size_t)orow * Nn + ocol] = f2us_rtn(v);
                    ps[mi][r] = fmaf(v, asv, ps[mi][r]);
                    pd[mi][r] = fmaf(v, adv, pd[mi][r]);
                }
            }
        }
    }
#pragma unroll
    for (int mi = 0; mi < 2; mi++)
#pragma unroll
        for (int r = 0; r < 4; r++)
#pragma unroll
            for (int off = 1; off < 16; off <<= 1) {
                ps[mi][r] += __shfl_xor(ps[mi][r], off);
                pd[mi][r] += __shfl_xor(pd[mi][r], off);
            }
    if (m16 == 0) {
#pragma unroll
        for (int mi = 0; mi < 2; mi++) {
            const int orow_base = row0 + wr + mi * 16 + quad * 4;
#pragma unroll
            for (int r = 0; r < 4; r++) {
                const int orow = orow_base + r;
                if (orow < M) {
                    atomicAdd(&as_[orow], ps[mi][r]);
                    atomicAdd(&ad_[orow], pd[mi][r]);
                }
            }
        }
    }
}

// ---- k2: gemm1-blocks || count-blocks (block partition, NO fence/handshake).
// R10-proven; (256,1) frees the register allocator (R6/R7: merged kernels
// otherwise get VGPR pinned to 52-64 -> scratch spill).
__global__ __launch_bounds__(256, 1) void gemm1_count(const unsigned short* __restrict__ A,
                                                      const unsigned short* __restrict__ Bt,
                                                      const float* __restrict__ avs,
                                                      const float* __restrict__ avd,
                                                      float* __restrict__ as_,
                                                      float* __restrict__ ad_,
                                                      unsigned short* __restrict__ C,
                                                      int M, int Nn, int K, int ntiles,
                                                      const int* __restrict__ dstA,
                                                      int* __restrict__ deg, int E, int Etot) {
    __shared__ unsigned short sA[64 * LP];
    __shared__ unsigned short sB[128 * LP];
    const int bid = blockIdx.x;
    if (bid < ntiles) {
        gemm_tile(A, Bt, avs, avd, as_, ad_, C, M, Nn, K,
                  (bid >> 1) * 64, (bid & 1) * 128, sA, sB);
    } else {
        const int e = (bid - ntiles) * 256 + threadIdx.x;
        if (e < Etot) {
            const int d = (e < E) ? dstA[e] : (e - E);
            atomicAdd(&deg[d], 1);
        }
    }
}

// ---- standalone GAT gemm (layer 2, R1-proven) -------------------------------
__global__ __launch_bounds__(256) void gemm_mfma(const unsigned short* __restrict__ A,
                                                 const unsigned short* __restrict__ Bt,
                                                 const float* __restrict__ avs,
                                                 const float* __restrict__ avd,
                                                 float* __restrict__ as_,
                                                 float* __restrict__ ad_,
                                                 unsigned short* __restrict__ C,
                                                 int M, int Nn, int K) {
    __shared__ unsigned short sA[64 * LP];
    __shared__ unsigned short sB[128 * LP];
    gemm_tile(A, Bt, avs, avd, as_, ad_, C, M, Nn, K,
              blockIdx.x * 64, blockIdx.y * 128, sA, sB);
}

// ---------------- MLP gemm + fused head (proven R1 body) ---------------------
__global__ __launch_bounds__(256) void gemm_head(const unsigned short* __restrict__ A,
                                                 const unsigned short* __restrict__ Bt,
                                                 const float* __restrict__ bias1,
                                                 const float* __restrict__ W2,
                                                 const float* __restrict__ bias2,
                                                 float* __restrict__ out,
                                                 int M, int K, int Aout) {
    __shared__ unsigned short sA[64 * LP];
    __shared__ unsigned short sB[256 * LP];
    __shared__ float pLDS[2][64][8];
    const int tid = threadIdx.x;
    const int wave = tid >> 6, lane = tid & 63;
    const int m16 = lane & 15, quad = lane >> 4;
    const int row0 = blockIdx.x * 64;
    const int wr = (wave >> 1) * 32, wc = (wave & 1) * 128;
    const int ar = tid >> 2, akc = (tid & 3) * 8;
    const int bkc = (tid & 7) * 8, bcb = tid >> 3;
    const int gr = (row0 + ar) < M ? (row0 + ar) : (M - 1);
    const unsigned short* Arow = A + (size_t)gr * K + akc;
    const unsigned short* Bcol = Bt + (size_t)bcb * K + bkc;

    short8 rA0, rA1, rb[8];
    auto LOADT = [&](int k0) {
        rA0 = *(const short8*)(Arow + k0);
        rA1 = *(const short8*)(Arow + k0 + 32);
#pragma unroll
        for (int q = 0; q < 8; q++)
            rb[q] = *(const short8*)(Bcol + (size_t)(32 * q) * K + k0);
    };
    auto STORET = [&]() {
        *(short8*)&sA[ar * LP + akc]      = rA0;
        *(short8*)&sA[ar * LP + akc + 32] = rA1;
#pragma unroll
        for (int q = 0; q < 8; q++)
            *(short8*)&sB[(bcb + 32 * q) * LP + bkc] = rb[q];
    };

    f32x4 acc[2][8] = {};
    LOADT(0);
    STORET();
    __syncthreads();
    for (int k0 = 0; k0 < K; k0 += 64) {
        const bool more = (k0 + 64) < K;
        if (more) LOADT(k0 + 64);
#pragma unroll
        for (int ks = 0; ks < 2; ks++) {
            short8 ah[2];
#pragma unroll
            for (int mi = 0; mi < 2; mi++)
                ah[mi] = *(const short8*)&sA[(wr + mi * 16 + m16) * LP + ks * 32 + quad * 8];
#pragma unroll
            for (int ni = 0; ni < 8; ni++) {
                const short8 bv = *(const short8*)&sB[(wc + ni * 16 + m16) * LP + ks * 32 + quad * 8];
#pragma unroll
                for (int mi = 0; mi < 2; mi++)
                    acc[mi][ni] = __builtin_amdgcn_mfma_f32_16x16x32_bf16(ah[mi], bv, acc[mi][ni], 0, 0, 0);
            }
        }
        __syncthreads();
        if (more) { STORET(); __syncthreads(); }
    }
    float p[2][4][8] = {};
#pragma unroll
    for (int ni = 0; ni < 8; ni++) {
        const int ocol = wc + ni * 16 + m16;
        const float b1v = bias1[ocol];
        float w2[8];
#pragma unroll
        for (int a = 0; a < 8; a++) w2[a] = W2[ocol * 8 + a];
#pragma unroll
        for (int mi = 0; mi < 2; mi++)
#pragma unroll
            for (int r = 0; r < 4; r++) {
                const float v = fmaxf(acc[mi][ni][r] + b1v, 0.f);
#pragma unroll
                for (int a = 0; a < 8; a++) p[mi][r][a] = fmaf(v, w2[a], p[mi][r][a]);
            }
    }
#pragma unroll
    for (int off = 1; off < 16; off <<= 1)
#pragma unroll
        for (int mi = 0; mi < 2; mi++)
#pragma unroll
            for (int r = 0; r < 4; r++)
#pragma unroll
                for (int a = 0; a < 8; a++) p[mi][r][a] += __shfl_xor(p[mi][r][a], off);
    if (m16 == 0) {
        const int half = wc >> 7;
#pragma unroll
        for (int mi = 0; mi < 2; mi++) {
            const int lrow = wr + mi * 16 + quad * 4;
#pragma unroll
            for (int r = 0; r < 4; r++)
#pragma unroll
                for (int a = 0; a < 8; a++) pLDS[half][lrow + r][a] = p[mi][r][a];
        }
    }
    __syncthreads();
#pragma unroll
    for (int u = 0; u < 2; u++) {
        const int idx = tid * 2 + u;
        const int lrow = idx >> 3, a = idx & 7;
        const int orow = row0 + lrow;
        if (orow < M && a < Aout)
            out[(size_t)orow * Aout + a] =
                tanhf(pLDS[0][lrow][a] + pLDS[1][lrow][a] + bias2[a]);
    }
}
#undef LP

// 256-thread int4 scan over padded deg (R9-proven) ----------------------------
__global__ __launch_bounds__(256) void scan_kernel(const int* __restrict__ deg,
                                                   int* __restrict__ offs,
                                                   int* __restrict__ cursor, int N, int per) {
    __shared__ int sums[256];
    const int t = threadIdx.x;
    const int base = t * per;
    int s = 0;
    for (int i = 0; i < per; i += 4) {
        const int4 v = *(const int4*)(deg + base + i);
        s += v.x + v.y + v.z + v.w;
    }
    sums[t] = s;
    __syncthreads();
    for (int off = 1; off < 256; off <<= 1) {
        const int add = (t >= off) ? sums[t - off] : 0;
        __syncthreads();
        sums[t] += add;
        __syncthreads();
    }
    int run = (t > 0) ? sums[t - 1] : 0;
    for (int i = 0; i < per; i += 4) {
        const int4 v = *(const int4*)(deg + base + i);
        const int p = base + i;
        const int vv[4] = {v.x, v.y, v.z, v.w};
#pragma unroll
        for (int j = 0; j < 4; j++) {
            if (p + j < N) { offs[p + j] = run; cursor[p + j] = run; }
            run += vv[j];
        }
    }
    if (t == 255) offs[N] = run;   // pads are zero -> run == total
}

__global__ void scatter_kernel(const int* __restrict__ srcA, const int* __restrict__ dstA,
                               int* __restrict__ cursor, int* __restrict__ esrc, int E, int Etot) {
    const int e = blockIdx.x * blockDim.x + threadIdx.x;
    if (e >= Etot) return;
    int s, d;
    if (e < E) { s = srcA[e]; d = dstA[e]; } else { s = d = e - E; }
    const int slot = atomicAdd(&cursor[d], 1);
    esrc[slot] = s;
}

// ---- fused softmax+aggregation (R10-proven: tail-guarded gathers) -----------
__global__ __launch_bounds__(256) void agg_kernel(const unsigned short* __restrict__ hb,
                                                  const int* __restrict__ offs,
                                                  const int* __restrict__ esrc,
                                                  const float* __restrict__ as_,
                                                  const float* __restrict__ ad_,
                                                  const float* __restrict__ bias,
                                                  unsigned short* __restrict__ xout, int N) {
    const int n = __builtin_amdgcn_readfirstlane(blockIdx.x * 4 + (threadIdx.x >> 6));
    if (n >= N) return;
    const int lane = threadIdx.x & 63;
    const int half = lane >> 5;
    const int f0 = (lane & 31) * 8;
    const int b = offs[n], e2 = offs[n + 1];
    const float adn = ad_[n];
    float a[8] = {};
    float wsum = 0.f;
    for (int c0 = b; c0 < e2; c0 += 16) {
        const int rem = e2 - c0;
        const int lim = rem < 16 ? rem : 16;
        int s = 0;
        float w = 0.f;
        if (lane < 16) {
            const int j = c0 + lane;
            const int jj = j < e2 ? j : e2 - 1;     // self-loop guarantees >= 1 edge
            s = esrc[jj];
            if (j < e2) {
                float v = as_[s] + adn;
                v = v > 0.f ? v : 0.2f * v;
                w = __expf(v);
                wsum += w;
            }
        }
        us8 pv[8];
        float wb[8];
#pragma unroll
        for (int u = 0; u < 8; u++) {
            const int el = 2 * u + half;
            const int su = __shfl(s, el);
            wb[u] = __shfl(w, el);
            if (el < lim)
                pv[u] = *(const us8*)(hb + (unsigned)((su << 8) + f0));
        }
#pragma unroll
        for (int u = 0; u < 8; u++) {
            if (2 * u + half < lim) {
#pragma unroll
                for (int j2 = 0; j2 < 8; j2++)
                    a[j2] = fmaf(wb[u], us2f(pv[u][j2]), a[j2]);
            }
        }
    }
#pragma unroll
    for (int j2 = 0; j2 < 8; j2++) a[j2] += __shfl_xor(a[j2], 32);
#pragma unroll
    for (int off = 32; off; off >>= 1) wsum += __shfl_xor(wsum, off);
    const float inv = 1.0f / (wsum + 1e-16f);
    if (half == 0) {
        const float4 b0 = *(const float4*)(bias + f0);
        const float4 b1 = *(const float4*)(bias + f0 + 4);
        const float bb[8] = {b0.x, b0.y, b0.z, b0.w, b1.x, b1.y, b1.z, b1.w};
        us8 o;
#pragma unroll
        for (int j2 = 0; j2 < 8; j2++)
            o[j2] = f2us_rtn(fmaxf(a[j2] * inv + bb[j2], 0.f));
        *(us8*)(xout + (unsigned)((n << 8) + f0)) = o;
    }
}

extern "C" void kernel_launch(void* const* d_in, const int* in_sizes, int n_in,
                              void* d_out, int out_size, void* d_ws, size_t ws_size,
                              hipStream_t stream) {
    const float* obs = (const float*)d_in[0];
    const int* eidx  = (const int*)d_in[1];
    const float* W1  = (const float*)d_in[2];
    const float* a1s = (const float*)d_in[3];
    const float* a1d = (const float*)d_in[4];
    const float* b1  = (const float*)d_in[5];
    const float* W2  = (const float*)d_in[6];
    const float* a2s = (const float*)d_in[7];
    const float* a2d = (const float*)d_in[8];
    const float* b2v = (const float*)d_in[9];
    const float* Wm1 = (const float*)d_in[10];
    const float* bm1 = (const float*)d_in[11];
    const float* Wm2 = (const float*)d_in[12];
    const float* bm2 = (const float*)d_in[13];
    float* out = (float*)d_out;

    const int Hh = in_sizes[3];            // 256
    const int Dd = in_sizes[2] / Hh;       // 256
    const int N  = in_sizes[0] / Dd;       // 20000
    const int E  = in_sizes[1] / 2;        // 320000
    const int Etot = E + N;                // 340000 (with self-loops)
    const int Aout = in_sizes[12] / Hh;    // 8

    const int* srcA = eidx;
    const int* dstA = eidx + E;

    // 256-thread scan geometry
    int per = (N + 255) / 256;
    per = (per + 3) & ~3;                  // multiple of 4 (int4 loads)
    const int Npad = 256 * per;            // 20480 at N=20000

    size_t off = 0;
    char* ws = (char*)d_ws;
    auto alloc = [&](size_t bytes) -> char* {
        char* p = ws + off;
        off = (off + bytes + 15) & ~(size_t)15;
        return p;
    };
    unsigned short* h    = (unsigned short*)alloc((size_t)N * Hh * 2);
    unsigned short* xb   = (unsigned short*)alloc((size_t)N * Hh * 2);
    unsigned short* obsb = (unsigned short*)alloc((size_t)N * Dd * 2);
    float* as1   = (float*)alloc((size_t)N * 4);
    float* ad1   = (float*)alloc((size_t)N * 4);
    float* as2   = (float*)alloc((size_t)N * 4);
    float* ad2   = (float*)alloc((size_t)N * 4);
    int* deg     = (int*)alloc((size_t)Npad * 4);
    int* offs    = (int*)alloc((size_t)(N + 1) * 4);
    int* cursor  = (int*)alloc((size_t)N * 4);
    int* esrc    = (int*)alloc((size_t)Etot * 4);
    const size_t wsz = (size_t)Dd * Hh;    // 65536
    unsigned short* W1t = (unsigned short*)alloc(wsz * 2);
    unsigned short* W2t = (unsigned short*)alloc(wsz * 2);
    unsigned short* Wmt = (unsigned short*)alloc(wsz * 2);

    const int eb = 256;
    const int eg = (Etot + eb - 1) / eb;         // 1329
    const int nrow = (N + 63) / 64;              // 313
    const int ntiles = nrow * (Hh / 128);        // 626 (64x128 tiles)
    const dim3 ggrid(nrow, Hh / 128);            // 313 x 2
    const int nb4 = (N + 3) / 4;
    const int nObs8 = N * Dd / 8;                // 640000

    // ---- k1: prep (W^T bf16, obs->bf16, zero-init) ----
    const int ptot = 3 * (int)wsz + 4 * N + Npad + nObs8;
    prep_zero<<<(ptot + 255) / 256, 256, 0, stream>>>(
        W1, W2, Wm1, obs, W1t, W2t, Wmt, obsb, as1, ad1, as2, ad2, deg,
        Dd, Hh, N, Npad, nObs8);

    // ---- k2: gemm1 || count (block-partitioned, no sync) ----
    gemm1_count<<<ntiles + eg, 256, 0, stream>>>(
        obsb, W1t, a1s, a1d, as1, ad1, h, N, Hh, Dd, ntiles,
        dstA, deg, E, Etot);

    // ---- k3: scan ----
    scan_kernel<<<1, 256, 0, stream>>>(deg, offs, cursor, N, per);

    // ---- k4: scatter ----
    scatter_kernel<<<eg, eb, 0, stream>>>(srcA, dstA, cursor, esrc, E, Etot);

    // ---- k5: agg1 ----
    agg_kernel<<<nb4, 256, 0, stream>>>(h, offs, esrc, as1, ad1, b1, xb, N);

    // ---- k6: GAT layer 2 gemm ----
    gemm_mfma<<<ggrid, 256, 0, stream>>>(xb, W2t, a2s, a2d, as2, ad2, h, N, Hh, Hh);

    // ---- k7: agg2 ----
    agg_kernel<<<nb4, 256, 0, stream>>>(h, offs, esrc, as2, ad2, b2v, xb, N);

    // ---- k8: MLP + head (fused) ----
    gemm_head<<<nrow, 256, 0, stream>>>(xb, Wmt, bm1, Wm2, bm2, out, N, Hh, Aout);
}